// Round 1
// 9582.940 us; speedup vs baseline: 1.8795x; 1.8795x over previous
//
#include <hip/hip_runtime.h>
#include <cstdint>
#include <cstddef>

// MultiLayerLSTM on gfx950 — round 5: layer-wavefront pipelined persistent
// kernel. All 4 layers run concurrently on 256 blocks (64 per layer, 1/CU)
// with a 1-round skew: at global round r, layer l processes t = r - l.
// Serial chain drops from L*T=1024 grid-sync rounds to T+L-1=259.
// The input projection (Wih @ h_{l-1,t}) is computed in-kernel (second
// register-resident weight slice), so the per-layer gx GEMMs are gone.
// L=4 layers, B=64, T=256, D=H=1024.

#define LL 4
#define BB 64
#define TT 256
#define DD 1024
#define HH 1024
#define FOURH 4096
#define APAD 1032   // padded LDS row stride (bf16 elems)

typedef __bf16 bf16;
typedef __bf16 bf16x8 __attribute__((ext_vector_type(8)));
typedef __bf16 bf16x4 __attribute__((ext_vector_type(4)));
typedef __bf16 bf16x2 __attribute__((ext_vector_type(2)));
typedef float f32x4 __attribute__((ext_vector_type(4)));

__device__ __forceinline__ void async_load16(const void* g, void* l) {
    __builtin_amdgcn_global_load_lds(
        (const __attribute__((address_space(1))) unsigned int*)g,
        (__attribute__((address_space(3))) unsigned int*)l,
        16, 0, 0);
}

__device__ __forceinline__ f32x4 mfma_bf16(bf16x8 a, bf16x8 b, f32x4 c) {
    return __builtin_amdgcn_mfma_f32_16x16x32_bf16(a, b, c, 0, 0, 0);
}

__device__ __forceinline__ float fsig(float x) {
    return 1.f / (1.f + __expf(-x));
}
__device__ __forceinline__ float ftanh(float x) {
    x = fminf(10.f, fmaxf(-10.f, x));
    float e = __expf(2.f * x);
    return (e - 1.f) / (e + 1.f);
}

// ---------------- f32 -> bf16 convert (vectorized x4) ----------------
__global__ void cvt_f32_bf16(const float* __restrict__ in, bf16* __restrict__ out, int n4) {
    int i = blockIdx.x * blockDim.x + threadIdx.x;
    if (i < n4) {
        float4 v = ((const float4*)in)[i];
        bf16x4 o = { (bf16)v.x, (bf16)v.y, (bf16)v.z, (bf16)v.w };
        ((bf16x4*)out)[i] = o;
    }
}

// x [B][T][D] f32 -> x_bf [T][B][D] bf16. One block per (b,t) row.
__global__ __launch_bounds__(256) void cvt_x_transpose(
    const float* __restrict__ x, bf16* __restrict__ out) {
    int bx = blockIdx.x;           // = b*TT + t
    int b = bx >> 8, t = bx & 255;
    int tid = threadIdx.x;
    float4 v = ((const float4*)(x + (size_t)bx * DD))[tid];
    bf16x4 o = { (bf16)v.x, (bf16)v.y, (bf16)v.z, (bf16)v.w };
    ((bf16x4*)(out + ((size_t)(t * BB + b)) * DD))[tid] = o;
}

// ---------------- GEMM: C[M,N] = A[M,K] @ W[N,K]^T + bias[N] ----------------
// REMAP: output row m = t*B+b is written to row b*TT+t (f32 logits in [B][T]).
template <bool OUT_BF16, bool REMAP>
__global__ __launch_bounds__(256) void gemm_bt(
    const bf16* __restrict__ A, const bf16* __restrict__ W,
    const float* __restrict__ bias, void* __restrict__ Cout,
    int M, int N, int K)
{
    __shared__ bf16 As[128 * 32];
    __shared__ bf16 Bs[128 * 32];
    const int tid = threadIdx.x;
    const int wave = tid >> 6, lane = tid & 63;
    const int lmod = lane & 15, lhalf = lane >> 4;
    const int m0 = blockIdx.y * 128, n0 = blockIdx.x * 128;
    const int wr = (wave >> 1) * 64, wc = (wave & 1) * 64;

    f32x4 acc[4][4] = {};

    const int arow = tid >> 2;
    const int acol = (tid & 3) * 8;
    const bf16* Ab  = A + (size_t)(m0 + arow) * K + acol;
    const bf16* Ab2 = A + (size_t)(m0 + 64 + arow) * K + acol;
    const bf16* Wb  = W + (size_t)(n0 + arow) * K + acol;
    const bf16* Wb2 = W + (size_t)(n0 + 64 + arow) * K + acol;

    for (int kc = 0; kc < K; kc += 32) {
        async_load16(Ab + kc,  &As[tid * 8]);
        async_load16(Ab2 + kc, &As[2048 + tid * 8]);
        async_load16(Wb + kc,  &Bs[tid * 8]);
        async_load16(Wb2 + kc, &Bs[2048 + tid * 8]);
        __syncthreads();

        bf16x8 af[4], bfr[4];
#pragma unroll
        for (int mt = 0; mt < 4; mt++)
            af[mt] = *(const bf16x8*)&As[(wr + mt * 16 + lmod) * 32 + lhalf * 8];
#pragma unroll
        for (int nt = 0; nt < 4; nt++)
            bfr[nt] = *(const bf16x8*)&Bs[(wc + nt * 16 + lmod) * 32 + lhalf * 8];
#pragma unroll
        for (int mt = 0; mt < 4; mt++)
#pragma unroll
            for (int nt = 0; nt < 4; nt++)
                acc[mt][nt] = mfma_bf16(af[mt], bfr[nt], acc[mt][nt]);
        __syncthreads();
    }

#pragma unroll
    for (int mt = 0; mt < 4; mt++) {
#pragma unroll
        for (int nt = 0; nt < 4; nt++) {
            int n = n0 + wc + nt * 16 + lmod;
            float bv = bias[n];
#pragma unroll
            for (int r = 0; r < 4; r++) {
                int m = m0 + wr + mt * 16 + lhalf * 4 + r;
                int orow = REMAP ? ((m & 63) * TT + (m >> 6)) : m;
                float v = acc[mt][nt][r] + bv;
                if (OUT_BF16)
                    ((bf16*)Cout)[(size_t)orow * N + n] = (bf16)v;
                else
                    ((float*)Cout)[(size_t)orow * N + n] = v;
            }
        }
    }
}

// ---------------- Pipelined persistent LSTM kernel (all layers) ----------------
// 256 blocks x 256 threads, 1 block/CU. layer = bid>>6, block owns 16 hidden
// units (j0). Wave w = gate w; Wih and Whh row-slices both in VGPRs (2x128).
// Per round r (t = r-layer): wait input flag (layer-1 peers) -> stage
// h_{l-1,t} slab -> Wih MFMA -> wait own-peer flags -> stage h_{l,t-1} slab
// -> Whh MFMA -> gate exchange in LDS -> fused cell update -> publish h to
// hseq_l[t] -> release fence + flag. Flags are monotonic round counters;
// nothing is ever overwritten, so skew between layers is harmless.
__global__ __launch_bounds__(256, 1) void lstm_pipe(
    const bf16* __restrict__ x_bf,     // [T*B, D] layer-0 input slabs
    const bf16* __restrict__ h0_all,   // [L, B*H] initial h (bf16)
    const float* __restrict__ c0_all,  // [L, B*H] initial c (f32)
    const bf16* __restrict__ wih,      // [L, 4H, H]
    const bf16* __restrict__ whh,      // [L, 4H, H]
    const float* __restrict__ bias,    // [L, 4H]
    bf16* __restrict__ hseq_base,      // [L, T*B, H]
    float* __restrict__ outH, float* __restrict__ outC,  // [L, B*H]
    int* __restrict__ flags)           // [256], zeroed
{
    __shared__ bf16 As[64 * APAD];       // 132 KB padded A-slab (shared by both matmuls)
    __shared__ float Gs[4 * 64 * 17];    // 17.4 KB gate exchange

    const int tid = threadIdx.x;
    const int wave = tid >> 6, lane = tid & 63;
    const int lmod = lane & 15, lhalf = lane >> 4;
    const int bid = blockIdx.x;
    const int layer = bid >> 6;
    const int j0 = (bid & 63) * 16;

    const size_t SLAB = (size_t)TT * BB * HH;
    const bf16* inseq = (layer == 0) ? x_bf : (hseq_base + (size_t)(layer - 1) * SLAB);
    bf16* hseq = hseq_base + (size_t)layer * SLAB;
    const bf16* h0 = h0_all + (size_t)layer * BB * HH;
    const float* c0 = c0_all + (size_t)layer * BB * HH;
    float* oH = outH + (size_t)layer * BB * HH;
    float* oC = outC + (size_t)layer * BB * HH;
    int* inflags = flags + (layer - 1) * 64;   // only deref'd when layer > 0
    int* myflags = flags + layer * 64;

    // per-lane gate bias (column = this lane's gate-unit)
    const float bv = bias[layer * FOURH + wave * 1024 + j0 + lmod];

    // persistent weight fragments: wave w = gate w, unit row j0+lmod
    bf16x8 wI[32], wH[32];
    {
        const size_t row = (size_t)layer * FOURH + wave * 1024 + j0 + lmod;
        const bf16* wrI = wih + row * 1024 + lhalf * 8;
        const bf16* wrH = whh + row * 1024 + lhalf * 8;
#pragma unroll
        for (int kc = 0; kc < 32; kc++) {
            wI[kc] = *(const bf16x8*)(wrI + kc * 32);
            wH[kc] = *(const bf16x8*)(wrH + kc * 32);
        }
    }

    // persistent cell state: thread owns (m, jj) and (m, jj+1) at p=q*512+tid*2
    float2 creg[2];
#pragma unroll
    for (int q = 0; q < 2; q++) {
        int p = q * 512 + tid * 2;
        creg[q] = *(const float2*)&c0[(p >> 4) * 1024 + j0 + (p & 15)];
    }

    for (int t = 0; t < TT; t++) {
        const int r = t + layer;

        // ---- input-side: wait layer-1 peers (normally pre-satisfied), stage, Wih MFMA
        if (layer > 0) {
            if (wave == 0) {
                for (;;) {
                    int v = __hip_atomic_load(&inflags[lane], __ATOMIC_RELAXED,
                                              __HIP_MEMORY_SCOPE_AGENT);
                    if (__all(v >= r)) break;
                }
            }
            __syncthreads();
            __builtin_amdgcn_fence(__ATOMIC_ACQUIRE, "agent");
        }
        {
            const bf16* src = inseq + (size_t)t * (BB * HH);
#pragma unroll 8
            for (int i = 0; i < 32; i++) {
                int e = i * 2048 + tid * 8;
                bf16x8 v = *(const bf16x8*)(src + e);
                *(bf16x8*)&As[(e >> 10) * APAD + (e & 1023)] = v;
            }
        }
        __syncthreads();

        f32x4 acc[4] = {};
#pragma unroll
        for (int kc = 0; kc < 32; kc++) {
#pragma unroll
            for (int mt = 0; mt < 4; mt++) {
                bf16x8 a = *(const bf16x8*)&As[(mt * 16 + lmod) * APAD + kc * 32 + lhalf * 8];
                acc[mt] = mfma_bf16(a, wI[kc], acc[mt]);
            }
        }
        __syncthreads();   // all waves done reading As before restage

        // ---- recurrent side: wait own peers, stage h_{t-1}, Whh MFMA
        if (t > 0) {
            if (wave == 0) {
                for (;;) {
                    int v = __hip_atomic_load(&myflags[lane], __ATOMIC_RELAXED,
                                              __HIP_MEMORY_SCOPE_AGENT);
                    if (__all(v >= r)) break;
                }
            }
            __syncthreads();
            __builtin_amdgcn_fence(__ATOMIC_ACQUIRE, "agent");
        }
        {
            const bf16* src = (t == 0) ? h0 : (hseq + (size_t)(t - 1) * BB * HH);
#pragma unroll 8
            for (int i = 0; i < 32; i++) {
                int e = i * 2048 + tid * 8;
                bf16x8 v = *(const bf16x8*)(src + e);
                *(bf16x8*)&As[(e >> 10) * APAD + (e & 1023)] = v;
            }
        }
        __syncthreads();

#pragma unroll
        for (int kc = 0; kc < 32; kc++) {
#pragma unroll
            for (int mt = 0; mt < 4; mt++) {
                bf16x8 a = *(const bf16x8*)&As[(mt * 16 + lmod) * APAD + kc * 32 + lhalf * 8];
                acc[mt] = mfma_bf16(a, wH[kc], acc[mt]);
            }
        }

        // park gates (+bias) in LDS for the cross-wave exchange
#pragma unroll
        for (int mt = 0; mt < 4; mt++)
#pragma unroll
            for (int rr = 0; rr < 4; rr++) {
                int m = mt * 16 + lhalf * 4 + rr;
                Gs[(wave * 64 + m) * 17 + lmod] = acc[mt][rr] + bv;
            }
        __syncthreads();

        // fused cell update; publish h to hseq[t] slab (packed bf16x2)
        const bool lastt = (t == TT - 1);
#pragma unroll
        for (int q = 0; q < 2; q++) {
            int p = q * 512 + tid * 2;
            int m = p >> 4, jj = p & 15;
            float cv[2], hv[2];
#pragma unroll
            for (int u = 0; u < 2; u++) {
                float gi = Gs[(0 * 64 + m) * 17 + jj + u];
                float gf = Gs[(1 * 64 + m) * 17 + jj + u];
                float gg = Gs[(2 * 64 + m) * 17 + jj + u];
                float go = Gs[(3 * 64 + m) * 17 + jj + u];
                float cprev = u ? creg[q].y : creg[q].x;
                float c = fsig(gf) * cprev + fsig(gi) * ftanh(gg);
                float h = fsig(go) * ftanh(c);
                cv[u] = c; hv[u] = h;
            }
            creg[q].x = cv[0]; creg[q].y = cv[1];
            bf16x2 hp = { (bf16)hv[0], (bf16)hv[1] };
            *(bf16x2*)&hseq[((size_t)(t * BB + m)) * HH + j0 + jj] = hp;
            if (lastt) {
                *(float2*)&oH[m * 1024 + j0 + jj] = make_float2(hv[0], hv[1]);
                *(float2*)&oC[m * 1024 + j0 + jj] = make_float2(cv[0], cv[1]);
            }
        }

        // publish: drain stores (syncthreads waits vmcnt), release, own flag
        __syncthreads();
        if (tid == 0) {
            __builtin_amdgcn_fence(__ATOMIC_RELEASE, "agent");
            __hip_atomic_store(&flags[bid], r + 1, __ATOMIC_RELAXED,
                               __HIP_MEMORY_SCOPE_AGENT);
        }
    }
}

extern "C" void kernel_launch(void* const* d_in, const int* in_sizes, int n_in,
                              void* d_out, int out_size, void* d_ws, size_t ws_size,
                              hipStream_t stream) {
    const float* x    = (const float*)d_in[0];
    const float* h0   = (const float*)d_in[1];
    const float* c0   = (const float*)d_in[2];
    const float* Wih  = (const float*)d_in[3];
    const float* Whh  = (const float*)d_in[4];
    const float* bias = (const float*)d_in[5];
    const float* Wout = (const float*)d_in[6];
    const float* bout = (const float*)d_in[7];

    // ---- workspace layout (~226.5 MB) ----
    char* p = (char*)d_ws;
    int*  ctrs    = (int*)p;  p += 1024;                             // 256 flags
    bf16* x_bf    = (bf16*)p; p += (size_t)BB * TT * DD * 2;         // 32 MB ([T][B][D])
    bf16* hseq    = (bf16*)p; p += (size_t)LL * BB * TT * HH * 2;    // 128 MB (per-layer slabs)
    bf16* wih_bf  = (bf16*)p; p += (size_t)LL * FOURH * HH * 2;      // 32 MB
    bf16* whh_bf  = (bf16*)p; p += (size_t)LL * FOURH * HH * 2;      // 32 MB
    bf16* wout_bf = (bf16*)p; p += (size_t)DD * HH * 2;              // 2 MB
    bf16* h0_bf   = (bf16*)p; p += (size_t)LL * BB * HH * 2;         // 0.5 MB
    if ((size_t)(p - (char*)d_ws) > ws_size) return;

    hipMemsetAsync(ctrs, 0, 1024, stream);

    // ---- convert inputs to bf16 ----
    cvt_x_transpose<<<BB * TT, 256, 0, stream>>>(x, x_bf);
    {
        struct { const float* in; bf16* out; size_t n; } jobs[4] = {
            { Wih,  wih_bf,  (size_t)LL * FOURH * HH },
            { Whh,  whh_bf,  (size_t)LL * FOURH * HH },
            { Wout, wout_bf, (size_t)DD * HH },
            { h0,   h0_bf,   (size_t)LL * BB * HH },
        };
        for (int j = 0; j < 4; j++) {
            int n4 = (int)(jobs[j].n / 4);
            cvt_f32_bf16<<<(n4 + 255) / 256, 256, 0, stream>>>(jobs[j].in, jobs[j].out, n4);
        }
    }

    float* logits = (float*)d_out;
    float* outH = logits + (size_t)BB * TT * DD;
    float* outC = outH + (size_t)LL * BB * HH;

    // ---- all 4 layers, pipelined, one persistent dispatch ----
    lstm_pipe<<<LL * 64, 256, 0, stream>>>(
        x_bf, h0_bf, c0, wih_bf, whh_bf, bias,
        hseq, outH, outC, ctrs);

    // ---- output projection from layer-3 hidden sequence ----
    dim3 g2(DD / 128, (BB * TT) / 128);
    gemm_bt<false, true><<<g2, 256, 0, stream>>>(
        hseq + (size_t)(LL - 1) * TT * BB * HH, wout_bf, bout, logits,
        BB * TT, DD, HH);
}